// Round 2
// baseline (164.313 us; speedup 1.0000x reference)
//
#include <hip/hip_runtime.h>

// out[b] = (x @ W^T).sum(axis=1) * (0.5 * 2.0) = sum_k x[b,k] * wsum[k],
// with wsum[k] = sum_h W[h,k].
//
// R3: single fused chunk kernel + tiny reduce. Key observation: the wsum
// dependency is per-column-chunk, not global. Block c owns a 16-float column
// chunk: phase A reads W[:, chunk_c] (256 KiB) and reduces to its 16 wsum
// values in-block; phase B reads x[:, chunk_c] and emits per-row partial dots
// pdot[c][b]. No grid sync, no atomics; blocks self-stagger so HBM stays
// saturated across the W->x transition (the 3-stage version drained BW twice).
// Total traffic: 64 MiB (W) + 64 MiB (x) + 4 MiB pdot round-trip ~= 20.6 us
// floor at 6.6 TB/s.

#define N 4096            // BATCH == INPUT_SIZE == HIDDEN_SIZE
#define N4 (N / 4)        // float4 per row
#define NCH 256           // column chunks == blocks (1 per CU)
#define CW4 4             // float4 per chunk (16 floats)
#define TPB 512           // 8 waves per block
#define RPI (TPB / 4)     // 128 rows per iteration
#define NIT (N / RPI)     // 32 iterations per phase

__global__ __launch_bounds__(TPB) void fused_chunk_kernel(
    const float* __restrict__ W, const float* __restrict__ x,
    float* __restrict__ pdot) {
    const int q    = threadIdx.x & 3;        // float4-column within chunk
    const int rl   = threadIdx.x >> 2;       // 0..127 local row
    const int c4   = blockIdx.x * CW4 + q;   // global float4 column
    const int wave = threadIdx.x >> 6;
    const int lane = threadIdx.x & 63;
    const float4* __restrict__ W4 = (const float4*)W;
    const float4* __restrict__ x4 = (const float4*)x;

    // ---- Phase A: wsum[chunk] = column sums of W over all 4096 rows ----
    float4 acc = make_float4(0.f, 0.f, 0.f, 0.f);
#pragma unroll 8
    for (int i = 0; i < NIT; ++i) {
        const int row = i * RPI + rl;
        float4 v = W4[(size_t)row * N4 + c4];
        acc.x += v.x; acc.y += v.y; acc.z += v.z; acc.w += v.w;
    }
    // reduce across the 16 lanes of this wave sharing q (lane bits 2..5)
#pragma unroll
    for (int off = 4; off <= 32; off <<= 1) {
        acc.x += __shfl_xor(acc.x, off, 64);
        acc.y += __shfl_xor(acc.y, off, 64);
        acc.z += __shfl_xor(acc.z, off, 64);
        acc.w += __shfl_xor(acc.w, off, 64);
    }
    __shared__ float4 ws[TPB / 64][4];
    __shared__ float4 wsum_s[4];
    if (lane < 4) ws[wave][lane] = acc;      // lane == q for lanes 0..3
    __syncthreads();
    if (threadIdx.x < 4) {
        float4 s = ws[0][threadIdx.x];
#pragma unroll
        for (int w = 1; w < TPB / 64; ++w) {
            float4 t = ws[w][threadIdx.x];
            s.x += t.x; s.y += t.y; s.z += t.z; s.w += t.w;
        }
        wsum_s[threadIdx.x] = s;
    }
    __syncthreads();
    const float4 wv = wsum_s[q];

    // ---- Phase B: pdot[c][b] = dot(x[b, chunk], wsum[chunk]) ----
    float* __restrict__ pc = pdot + (size_t)blockIdx.x * N;
#pragma unroll 8
    for (int i = 0; i < NIT; ++i) {
        const int row = i * RPI + rl;
        float4 xv = x4[(size_t)row * N4 + c4];
        float d = xv.x * wv.x + xv.y * wv.y + xv.z * wv.z + xv.w * wv.w;
        d += __shfl_xor(d, 1, 64);
        d += __shfl_xor(d, 2, 64);           // all 4 q-lanes now hold row dot
        if (q == 0) pc[row] = d;
    }
}

// out[b] = sum_c pdot[c][b]  (scale = 0.5 * 2.0 = 1.0)
__global__ __launch_bounds__(256) void pdot_reduce_kernel(
    const float* __restrict__ pdot, float* __restrict__ out) {
    const int b = blockIdx.x * 256 + threadIdx.x;
    float acc = 0.f;
#pragma unroll 16
    for (int c = 0; c < NCH; ++c)
        acc += pdot[(size_t)c * N + b];
    out[b] = acc * (0.5f * 2.0f);
}

extern "C" void kernel_launch(void* const* d_in, const int* in_sizes, int n_in,
                              void* d_out, int out_size, void* d_ws, size_t ws_size,
                              hipStream_t stream) {
    const float* x = (const float*)d_in[0];   // (4096, 4096) fp32
    const float* W = (const float*)d_in[1];   // (4096, 4096) fp32
    float* out = (float*)d_out;               // (4096, 1) fp32
    float* pdot = (float*)d_ws;               // NCH * N floats = 4 MiB

    fused_chunk_kernel<<<NCH, TPB, 0, stream>>>(W, x, pdot);
    pdot_reduce_kernel<<<N / 256, 256, 0, stream>>>(pdot, out);
}